// Round 17
// baseline (164.599 us; speedup 1.0000x reference)
//
#include <hip/hip_runtime.h>
#include <stdint.h>

typedef float  f32x4 __attribute__((ext_vector_type(4)));
typedef __bf16 bf16x8 __attribute__((ext_vector_type(8)));
typedef short  s16x8 __attribute__((ext_vector_type(8)));
typedef unsigned short u16;

static __device__ __forceinline__ u16 f2bf(float f) {
  unsigned u = __float_as_uint(f);
  u += 0x7fffu + ((u >> 16) & 1u);
  return (u16)(u >> 16);
}
static __device__ __forceinline__ float bf2f(u16 u) {
  return __uint_as_float(((unsigned)u) << 16);
}

static __device__ __forceinline__ void async_copy16(void* lds, const void* g) {
  __builtin_amdgcn_global_load_lds(
      (const __attribute__((address_space(1))) unsigned int*)g,
      (__attribute__((address_space(3))) unsigned int*)lds, 16, 0, 0);
}

// ------- fused LayerNorm (blocks < 16384) + weight cvt (blocks >= 16384) ----
__global__ __launch_bounds__(256) void ln_cvt_k(const float* __restrict__ x,
                                                const float* __restrict__ g,
                                                const float* __restrict__ b,
                                                u16* __restrict__ xn,
                                                const float* __restrict__ w0,
                                                const float* __restrict__ w1,
                                                u16* __restrict__ o0,
                                                u16* __restrict__ o1) {
  const int D = 1024, Mrows = 16384, n4 = 262144;
  const int tid = threadIdx.x;
  if (blockIdx.x >= Mrows) {
    int i = (blockIdx.x - Mrows) * 256 + tid;      // 0 .. 2*n4-1
    const float* in = (i < n4) ? w0 : w1;
    u16* out = (i < n4) ? o0 : o1;
    int idx = (i < n4) ? i : i - n4;
    float4 v = reinterpret_cast<const float4*>(in)[idx];
    ushort4 o;
    o.x = f2bf(v.x); o.y = f2bf(v.y); o.z = f2bf(v.z); o.w = f2bf(v.w);
    reinterpret_cast<ushort4*>(out)[idx] = o;
    return;
  }
  const int row = blockIdx.x;
  const float4 v = reinterpret_cast<const float4*>(x + (size_t)row * D)[tid];
  float s  = v.x + v.y + v.z + v.w;
  float s2 = v.x * v.x + v.y * v.y + v.z * v.z + v.w * v.w;
  #pragma unroll
  for (int off = 32; off > 0; off >>= 1) {
    s  += __shfl_down(s, off);
    s2 += __shfl_down(s2, off);
  }
  __shared__ float red[8];
  const int lane = tid & 63, wv = tid >> 6;
  if (lane == 0) { red[wv] = s; red[4 + wv] = s2; }
  __syncthreads();
  s  = red[0] + red[1] + red[2] + red[3];
  s2 = red[4] + red[5] + red[6] + red[7];
  const float mu   = s * (1.0f / D);
  const float var  = s2 * (1.0f / D) - mu * mu;
  const float rstd = rsqrtf(var + 1e-5f);
  const float4 gv = reinterpret_cast<const float4*>(g)[tid];
  const float4 bv = reinterpret_cast<const float4*>(b)[tid];
  ushort4 o;
  o.x = f2bf((v.x - mu) * rstd * gv.x + bv.x);
  o.y = f2bf((v.y - mu) * rstd * gv.y + bv.y);
  o.z = f2bf((v.z - mu) * rstd * gv.z + bv.z);
  o.w = f2bf((v.w - mu) * rstd * gv.w + bv.w);
  reinterpret_cast<ushort4*>(xn + (size_t)row * D)[tid] = o;
}

// ------ bf16 GEMM: 256^2, A via LDS (64 KiB dbuf), B direct from L2 --------
// B (2 MB weight) is L2/LLC-resident and reused 64x per block: staging it
// through LDS is pure overhead (guide mistake #7). B fragments load straight
// into VGPRs (per-wave: 16 rows x 64B contiguous = coalesced L2 hits).
// LDS 128->64 KiB => 2 blocks/CU. A keeps global_load_lds + XOR swizzle.
// Epilogue: 4 passes of 128x128 fp32 via LDS; MODE==1 bf16 out + fused
// T=64 EMA chunk partials.
template<int MODE>  // 0: fp32 out; 1: bf16 out + EMA partials
__global__ __launch_bounds__(512, 2) void gemm_bt_k(const u16* __restrict__ A,
                                                    const u16* __restrict__ Bm,
                                                    const float* __restrict__ bias,
                                                    void* __restrict__ Cv,
                                                    const float* __restrict__ alpha,
                                                    float* __restrict__ Lp,
                                                    int M, int N, int K) {
  const int tid  = threadIdx.x;
  const int lane = tid & 63;
  const int wv   = tid >> 6;      // 0..7
  const int wrr  = wv >> 2;       // 0..1  wave m-half
  const int wcc  = wv & 3;        // 0..3  wave n-quarter
  const int ntN  = N >> 8;
  const int nwg  = (M >> 8) * ntN;
  const int bid  = blockIdx.x;
  const int wgid = (bid & 7) * (nwg >> 3) + (bid >> 3);   // nwg % 8 == 0
  const int mt = wgid / ntN, nt = wgid % ntN;
  const int m0 = mt << 8, n0 = nt << 8;

  __shared__ __align__(16) u16 smem[32768];   // 64 KiB: A dbuf; later sC 128x128 f32

  // A staging: 4 rounds of 64 rows; u=tid>>3, tch=tid&7; inverse-swizzled src.
  const int u   = tid >> 3;
  const int tch = tid & 7;
  const int csw = (tch ^ (u & 7)) << 3;
  const int lofs = u * 64 + (tch << 3);
  const u16* gA = A + (size_t)(m0 + u) * K + csw;

  f32x4 acc[8][4];
  #pragma unroll
  for (int i = 0; i < 8; ++i)
    #pragma unroll
    for (int j = 0; j < 4; ++j) acc[i][j] = f32x4{0.f, 0.f, 0.f, 0.f};

  const int fr  = lane & 15;
  const int fkc = lane >> 4;
  const int sx  = fr & 7;
  // B fragment base: row = n0 + wcc*64 + j*16 + fr, elem = t*64 + s*32 + fkc*8
  const u16* gBf = Bm + (size_t)(n0 + wcc * 64 + fr) * K + (fkc << 3);
  const int nk  = K >> 6;
  int buf = 0;

  // prologue: stage A tile 0 into buf 0
  #pragma unroll
  for (int r = 0; r < 4; ++r)
    async_copy16(&smem[lofs + r * 4096], gA + (size_t)(r * 64) * K);
  __syncthreads();

  for (int t = 0; t < nk; ++t) {
    if (t + 1 < nk) {
      const size_t ko = (size_t)(t + 1) << 6;
      const int nb = (buf ^ 1) * 16384;
      #pragma unroll
      for (int r = 0; r < 4; ++r)
        async_copy16(&smem[nb + lofs + r * 4096], gA + ko + (size_t)(r * 64) * K);
    }
    // B fragments: direct global loads (L2-resident weight), coalesced
    s16x8 bfr[4][2];
    #pragma unroll
    for (int j = 0; j < 4; ++j)
      #pragma unroll
      for (int s = 0; s < 2; ++s)
        bfr[j][s] = *reinterpret_cast<const s16x8*>(
            gBf + (size_t)(j * 16) * K + t * 64 + s * 32);
    const u16* bA = smem + buf * 16384;
    #pragma unroll
    for (int s = 0; s < 2; ++s) {
      const int ch = ((((s << 2) + fkc) ^ sx) << 3);   // swizzled elem offset
      s16x8 af[8];
      #pragma unroll
      for (int i = 0; i < 8; ++i)
        af[i] = *reinterpret_cast<const s16x8*>(
            &bA[(wrr * 128 + i * 16 + fr) * 64 + ch]);
      #pragma unroll
      for (int i = 0; i < 8; ++i)
        #pragma unroll
        for (int j = 0; j < 4; ++j)
          acc[i][j] = __builtin_amdgcn_mfma_f32_16x16x32_bf16(
              __builtin_bit_cast(bf16x8, af[i]),
              __builtin_bit_cast(bf16x8, bfr[j][s]), acc[i][j], 0, 0, 0);
    }
    __syncthreads();   // drains vmcnt(0): next A tile staged, buf reusable
    buf ^= 1;
  }

  // ---- epilogue: 4 passes of 128x128 fp32 via 64 KiB LDS ------------------
  float* sC = (float*)smem;            // 128 x 128 fp32 = 64 KiB
  const int cr = (lane >> 4) << 2;
  const int cc = lane & 15;
  float bv[4];
  #pragma unroll
  for (int nj = 0; nj < 4; ++nj) bv[nj] = bias[n0 + wcc * 64 + nj * 16 + cc];

  #pragma unroll
  for (int p = 0; p < 2; ++p) {
    #pragma unroll
    for (int q = 0; q < 2; ++q) {
      __syncthreads();                 // K-loop / previous pass fully read
      if (wrr == p && (wcc >> 1) == q) {
        #pragma unroll
        for (int mi = 0; mi < 8; ++mi)
          #pragma unroll
          for (int nj = 0; nj < 4; ++nj)
            #pragma unroll
            for (int rr = 0; rr < 4; ++rr) {
              const int row = mi * 16 + cr + rr;
              const int col = (wcc & 1) * 64 + nj * 16 + cc;
              sC[row * 128 + (col ^ ((row & 4) << 2))] = acc[mi][nj][rr] + bv[nj];
            }
      }
      __syncthreads();
      // coalesced store: 16B/lane, 512B rows, 16 rows/iter x 8 iters
      #pragma unroll 4
      for (int it = 0; it < 8; ++it) {
        const int row  = it * 16 + (tid >> 5);
        const int col0 = (tid & 31) * 4;
        f32x4 v = *(const f32x4*)&sC[row * 128 + (col0 ^ ((row & 4) << 2))];
        const size_t goff = (size_t)(m0 + p * 128 + row) * N + n0 + q * 128 + col0;
        if (MODE == 1) {
          ushort4 o; o.x = f2bf(v[0]); o.y = f2bf(v[1]); o.z = f2bf(v[2]); o.w = f2bf(v[3]);
          *(ushort4*)&((u16*)Cv)[goff] = o;
        } else {
          *(f32x4*)&((float*)Cv)[goff] = v;
        }
      }
      if (MODE == 1 && tid < 256) {
        // T=64 chunks: col = tid&127 within this 128-col pass;
        // sub = tid>>7: 0 -> rows 0..63 (chunk 2p), 1 -> rows 64..127 (2p+1).
        // Chunk-boundary step (row 0/64) added exactly by carry_k.
        const int col = tid & 127;
        const int sub = tid >> 7;
        const int gcol = n0 + q * 128 + col;
        const float a  = 1.0f / (1.0f + __expf(-alpha[gcol >> 7]));
        const float rw = 1.0f - a;
        const int rbase = sub * 64 + 1;
        float prev = sC[(rbase - 1) * 128 + col];   // rows 0/64: (row&4)==0
        float L = 0.f;
        #pragma unroll 7
        for (int t = rbase; t < rbase + 63; ++t) {
          const float w = sC[t * 128 + (col ^ ((t & 4) << 2))];
          L = rw * L + a * (w - prev);
          prev = w;
        }
        const int bb = m0 >> 12;
        const int qb = (m0 >> 6) & 63;
        Lp[((size_t)bb * 64 + qb + 2 * p + sub) * 1024 + gcol] = L;
      }
    }
  }
}

// ------- EMA carry combine, T=64 (+ exact chunk-boundary terms) -----------
__global__ __launch_bounds__(256) void ema_carry_k(const u16* __restrict__ xpb,
                                                   const float* __restrict__ alpha,
                                                   const float* __restrict__ init,
                                                   float* __restrict__ carry) {
  const int Dd = 1024, nCh = 64;
  const int idx = blockIdx.x * 256 + threadIdx.x;  // 0..B*D-1
  const int c  = idx & (Dd - 1);
  const int bb = idx >> 10;
  const int h = c >> 7;
  const float a = 1.0f / (1.0f + __expf(-alpha[h]));
  const float r = 1.0f - a;
  float t_ = r, r63 = 1.0f;
  #pragma unroll
  for (int s = 0; s < 6; ++s) { r63 *= t_; t_ *= t_; }
  const float rT = r63 * r;    // r^64
  float cin = init[c];
  float prevv = cin;                               // v_{-1} for chunk 0
  #pragma unroll
  for (int batch = 0; batch < 2; ++batch) {
    float L[32], v0[32], vm[32];
    #pragma unroll
    for (int qq = 0; qq < 32; ++qq) {
      const int q = batch * 32 + qq;
      const size_t rowb = (size_t)bb * 4096 + (size_t)q * 64;
      L[qq]  = carry[((size_t)bb * nCh + q) * Dd + c];
      v0[qq] = bf2f(xpb[rowb * Dd + c]);
      vm[qq] = bf2f(xpb[(rowb + 63) * Dd + c]);
    }
    #pragma unroll
    for (int qq = 0; qq < 32; ++qq) {
      const int q = batch * 32 + qq;
      const float Lf = L[qq] + a * r63 * (v0[qq] - prevv);
      carry[((size_t)bb * nCh + q) * Dd + c] = cin;  // incoming O for chunk q
      cin = rT * cin + Lf;
      prevv = vm[qq];
    }
  }
}

// ------- EMA apply, T=64: 1024 blocks, 1 channel/thread -------------------
__global__ __launch_bounds__(256) void ema_apply_k(const u16* __restrict__ xp,
                                                   const float* __restrict__ alpha,
                                                   const float* __restrict__ init,
                                                   const float* __restrict__ carry,
                                                   u16* __restrict__ ob) {
  const int Nn = 4096, Dd = 1024, T = 64, nCh = 64;
  int bid = blockIdx.x;
  const int cg = bid & 3;  bid >>= 2;
  const int q  = bid & 63; bid >>= 6;
  const int bb = bid;
  const int c = cg * 256 + threadIdx.x;
  const int h = c >> 7;
  const float a = 1.0f / (1.0f + __expf(-alpha[h]));
  const float r = 1.0f - a;
  const u16* px = xp + ((size_t)bb * Nn + (size_t)q * T) * Dd + c;
  u16* po = ob + ((size_t)bb * Nn + (size_t)q * T) * Dd + c;
  float O = carry[((size_t)bb * nCh + q) * Dd + c];
  float p0 = (q == 0) ? init[c] : bf2f(px[-Dd]);
  #pragma unroll 4
  for (int t = 0; t < T; ++t) {
    const float v = bf2f(px[(size_t)t * Dd]);
    O = r * O + a * (v - p0);
    p0 = v;
    po[(size_t)t * Dd] = f2bf(O);
  }
}

extern "C" void kernel_launch(void* const* d_in, const int* in_sizes, int n_in,
                              void* d_out, int out_size, void* d_ws, size_t ws_size,
                              hipStream_t stream) {
  const float* x     = (const float*)d_in[0];
  const float* ln_g  = (const float*)d_in[1];
  const float* ln_b  = (const float*)d_in[2];
  const float* w_in  = (const float*)d_in[3];
  const float* b_in  = (const float*)d_in[4];
  const float* init  = (const float*)d_in[5];
  const float* alpha = (const float*)d_in[6];
  const float* w_out = (const float*)d_in[7];
  const float* b_out = (const float*)d_in[8];
  float* out = (float*)d_out;

  const int B = 4, N = 4096, D = 1024;
  const int M = B * N;  // 16384

  char* p = (char*)d_ws;
  u16*   xn  = (u16*)p; p += (size_t)M * D * sizeof(u16);      // 32 MB  LN out bf16
  u16*   wi  = (u16*)p; p += (size_t)D * D * sizeof(u16);      // 2 MB   w_in bf16
  u16*   wo  = (u16*)p; p += (size_t)D * D * sizeof(u16);      // 2 MB   w_out bf16
  u16*   xpb = (u16*)p; p += (size_t)M * D * sizeof(u16);      // 32 MB  xp bf16
  float* cr  = (float*)p; p += (size_t)B * 64 * D * sizeof(float); // 1 MB partials/carries
  u16*   ob  = (u16*)p;                                         // 32 MB  EMA out bf16

  // fused LN (16384 blocks) + both weight converts (2048 blocks)
  ln_cvt_k<<<dim3(M + 2048), dim3(256), 0, stream>>>(
      x, ln_g, ln_b, xn, w_in, w_out, wi, wo);
  gemm_bt_k<1><<<dim3((M / 256) * (D / 256)), dim3(512), 0, stream>>>(
      xn, wi, b_in, xpb, alpha, cr, M, D, D);
  ema_carry_k<<<dim3(B * D / 256), dim3(256), 0, stream>>>(xpb, alpha, init, cr);
  ema_apply_k<<<dim3(B * 64 * 4), dim3(256), 0, stream>>>(xpb, alpha, init, cr, ob);
  gemm_bt_k<0><<<dim3((M / 256) * (D / 256)), dim3(512), 0, stream>>>(
      ob, wo, b_out, out, nullptr, nullptr, M, D, D);
}

// Round 18
// 127.473 us; speedup vs baseline: 1.2912x; 1.2912x over previous
//
#include <hip/hip_runtime.h>
#include <stdint.h>

typedef float  f32x4 __attribute__((ext_vector_type(4)));
typedef __bf16 bf16x8 __attribute__((ext_vector_type(8)));
typedef short  s16x8 __attribute__((ext_vector_type(8)));
typedef unsigned short u16;

static __device__ __forceinline__ u16 f2bf(float f) {
  unsigned u = __float_as_uint(f);
  u += 0x7fffu + ((u >> 16) & 1u);
  return (u16)(u >> 16);
}
static __device__ __forceinline__ float bf2f(u16 u) {
  return __uint_as_float(((unsigned)u) << 16);
}

static __device__ __forceinline__ void async_copy16(void* lds, const void* g) {
  __builtin_amdgcn_global_load_lds(
      (const __attribute__((address_space(1))) unsigned int*)g,
      (__attribute__((address_space(3))) unsigned int*)lds, 16, 0, 0);
}

// ------- fused LayerNorm (blocks < 16384) + weight cvt (blocks >= 16384) ----
__global__ __launch_bounds__(256) void ln_cvt_k(const float* __restrict__ x,
                                                const float* __restrict__ g,
                                                const float* __restrict__ b,
                                                u16* __restrict__ xn,
                                                const float* __restrict__ w0,
                                                const float* __restrict__ w1,
                                                u16* __restrict__ o0,
                                                u16* __restrict__ o1) {
  const int D = 1024, Mrows = 16384, n4 = 262144;
  const int tid = threadIdx.x;
  if (blockIdx.x >= Mrows) {
    int i = (blockIdx.x - Mrows) * 256 + tid;      // 0 .. 2*n4-1
    const float* in = (i < n4) ? w0 : w1;
    u16* out = (i < n4) ? o0 : o1;
    int idx = (i < n4) ? i : i - n4;
    float4 v = reinterpret_cast<const float4*>(in)[idx];
    ushort4 o;
    o.x = f2bf(v.x); o.y = f2bf(v.y); o.z = f2bf(v.z); o.w = f2bf(v.w);
    reinterpret_cast<ushort4*>(out)[idx] = o;
    return;
  }
  const int row = blockIdx.x;
  const float4 v = reinterpret_cast<const float4*>(x + (size_t)row * D)[tid];
  float s  = v.x + v.y + v.z + v.w;
  float s2 = v.x * v.x + v.y * v.y + v.z * v.z + v.w * v.w;
  #pragma unroll
  for (int off = 32; off > 0; off >>= 1) {
    s  += __shfl_down(s, off);
    s2 += __shfl_down(s2, off);
  }
  __shared__ float red[8];
  const int lane = tid & 63, wv = tid >> 6;
  if (lane == 0) { red[wv] = s; red[4 + wv] = s2; }
  __syncthreads();
  s  = red[0] + red[1] + red[2] + red[3];
  s2 = red[4] + red[5] + red[6] + red[7];
  const float mu   = s * (1.0f / D);
  const float var  = s2 * (1.0f / D) - mu * mu;
  const float rstd = rsqrtf(var + 1e-5f);
  const float4 gv = reinterpret_cast<const float4*>(g)[tid];
  const float4 bv = reinterpret_cast<const float4*>(b)[tid];
  ushort4 o;
  o.x = f2bf((v.x - mu) * rstd * gv.x + bv.x);
  o.y = f2bf((v.y - mu) * rstd * gv.y + bv.y);
  o.z = f2bf((v.z - mu) * rstd * gv.z + bv.z);
  o.w = f2bf((v.w - mu) * rstd * gv.w + bv.w);
  reinterpret_cast<ushort4*>(xn + (size_t)row * D)[tid] = o;
}

// ---------------- bf16 GEMM, C = A @ B^T + bias: 256^2 2-PHASE (R9) --------
// BM=BN=256, BK=64, 512 threads (8 waves 2Mx4N), double-buffered 128 KiB LDS,
// ONE __syncthreads per K-step. XOR-swizzled LDS (linear dest + pre-swizzled
// src + swizzled read), XCD-bijective block swizzle. LDS-staged coalesced
// epilogue in 2 passes of 128 rows; MODE==1 bf16 out + fused EMA partials
// (T=64 chunks: each pass emits two independent 63-step partials).
template<int MODE>  // 0: fp32 out; 1: bf16 out + EMA partials
__global__ __launch_bounds__(512, 2) void gemm_bt_k(const u16* __restrict__ A,
                                                    const u16* __restrict__ Bm,
                                                    const float* __restrict__ bias,
                                                    void* __restrict__ Cv,
                                                    const float* __restrict__ alpha,
                                                    float* __restrict__ Lp,
                                                    int M, int N, int K) {
  const int tid  = threadIdx.x;
  const int lane = tid & 63;
  const int wv   = tid >> 6;      // 0..7
  const int wrr  = wv >> 2;       // 0..1  wave m-half
  const int wcc  = wv & 3;        // 0..3  wave n-quarter
  const int ntN  = N >> 8;
  const int nwg  = (M >> 8) * ntN;
  const int bid  = blockIdx.x;
  const int wgid = (bid & 7) * (nwg >> 3) + (bid >> 3);   // nwg % 8 == 0
  const int mt = wgid / ntN, nt = wgid % ntN;
  const int m0 = mt << 8, n0 = nt << 8;

  __shared__ __align__(16) u16 smem[65536];   // 128 KiB: A dbuf | B dbuf; later sC

  const int u   = tid >> 3;
  const int tch = tid & 7;
  const int csw = (tch ^ (u & 7)) << 3;
  const int lofs = u * 64 + (tch << 3);
  const u16* gA = A  + (size_t)(m0 + u) * K + csw;
  const u16* gB = Bm + (size_t)(n0 + u) * K + csw;

  f32x4 acc[8][4];
  #pragma unroll
  for (int i = 0; i < 8; ++i)
    #pragma unroll
    for (int j = 0; j < 4; ++j) acc[i][j] = f32x4{0.f, 0.f, 0.f, 0.f};

  const int fr  = lane & 15;
  const int fkc = lane >> 4;
  const int sx  = fr & 7;
  const int nk  = K >> 6;
  int buf = 0;

  // prologue: stage tile 0 into buf 0
  #pragma unroll
  for (int r = 0; r < 4; ++r) {
    async_copy16(&smem[lofs + r * 4096], gA + (size_t)(r * 64) * K);
    async_copy16(&smem[32768 + lofs + r * 4096], gB + (size_t)(r * 64) * K);
  }
  __syncthreads();

  for (int t = 0; t < nk; ++t) {
    if (t + 1 < nk) {
      const size_t ko = (size_t)(t + 1) << 6;
      const int nb = (buf ^ 1) * 16384;
      #pragma unroll
      for (int r = 0; r < 4; ++r) {
        async_copy16(&smem[nb + lofs + r * 4096], gA + ko + (size_t)(r * 64) * K);
        async_copy16(&smem[32768 + nb + lofs + r * 4096], gB + ko + (size_t)(r * 64) * K);
      }
    }
    const u16* bA = smem + buf * 16384;
    const u16* bB = smem + 32768 + buf * 16384;
    #pragma unroll
    for (int s = 0; s < 2; ++s) {
      const int ch = ((((s << 2) + fkc) ^ sx) << 3);   // swizzled elem offset
      s16x8 af[8], bfr[4];
      #pragma unroll
      for (int i = 0; i < 8; ++i)
        af[i] = *reinterpret_cast<const s16x8*>(
            &bA[(wrr * 128 + i * 16 + fr) * 64 + ch]);
      #pragma unroll
      for (int j = 0; j < 4; ++j)
        bfr[j] = *reinterpret_cast<const s16x8*>(
            &bB[(wcc * 64 + j * 16 + fr) * 64 + ch]);
      #pragma unroll
      for (int i = 0; i < 8; ++i)
        #pragma unroll
        for (int j = 0; j < 4; ++j)
          acc[i][j] = __builtin_amdgcn_mfma_f32_16x16x32_bf16(
              __builtin_bit_cast(bf16x8, af[i]),
              __builtin_bit_cast(bf16x8, bfr[j]), acc[i][j], 0, 0, 0);
    }
    __syncthreads();   // drains vmcnt(0): next tile staged, buf reusable
    buf ^= 1;
  }

  // ---- epilogue: 2 passes of 128 rows through LDS, coalesced stores -------
  float* sC = (float*)smem;            // 128 x 256 fp32 = 128 KiB
  const int cr = (lane >> 4) << 2;
  const int cc = lane & 15;
  float bv[4];
  #pragma unroll
  for (int nj = 0; nj < 4; ++nj) bv[nj] = bias[n0 + wcc * 64 + nj * 16 + cc];

  #pragma unroll
  for (int p = 0; p < 2; ++p) {
    __syncthreads();                   // K-loop / previous pass reads done
    if (wrr == p) {
      #pragma unroll
      for (int mi = 0; mi < 8; ++mi)
        #pragma unroll
        for (int nj = 0; nj < 4; ++nj)
          #pragma unroll
          for (int rr = 0; rr < 4; ++rr) {
            const int row = mi * 16 + cr + rr;
            const int col = wcc * 64 + nj * 16 + cc;
            sC[row * 256 + (col ^ ((row & 4) << 2))] = acc[mi][nj][rr] + bv[nj];
          }
    }
    __syncthreads();
    // coalesced store: 16B/lane, 1KB rows
    #pragma unroll 4
    for (int it = 0; it < 16; ++it) {
      const int row  = it * 8 + (tid >> 6);
      const int col0 = (tid & 63) * 4;
      f32x4 v = *(const f32x4*)&sC[row * 256 + (col0 ^ ((row & 4) << 2))];
      const size_t goff = (size_t)(m0 + p * 128 + row) * N + n0 + col0;
      if (MODE == 1) {
        ushort4 o; o.x = f2bf(v[0]); o.y = f2bf(v[1]); o.z = f2bf(v[2]); o.w = f2bf(v[3]);
        *(ushort4*)&((u16*)Cv)[goff] = o;
      } else {
        *(f32x4*)&((float*)Cv)[goff] = v;
      }
    }
    if (MODE == 1) {
      // T=64 chunks: lo half (tid<256) -> chunk 2p   (rows 0-63),  steps 1..63
      //              hi half           -> chunk 2p+1 (rows 64-127), steps 65..127
      // Chunk-boundary step (row 0 / row 64) is added exactly by carry_k.
      const int col = tid & 255;
      const int hh = (n0 + col) >> 7;
      const float a  = 1.0f / (1.0f + __expf(-alpha[hh]));
      const float rw = 1.0f - a;
      const bool lo = (tid < 256);
      const int rbase = lo ? 1 : 65;
      float prev = sC[(rbase - 1) * 256 + col];   // rows 0/64: (row&4)==0
      float L = 0.f;
      #pragma unroll 7
      for (int t = rbase; t < rbase + 63; ++t) {
        const float w = sC[t * 256 + (col ^ ((t & 4) << 2))];
        L = rw * L + a * (w - prev);
        prev = w;
      }
      const int bb = m0 >> 12;
      const int q  = ((m0 >> 6) & 63) + 2 * p + (lo ? 0 : 1);
      Lp[((size_t)bb * 64 + q) * 1024 + n0 + col] = L;
    }
  }
}

// ------- EMA carry combine, T=64 (+ exact chunk-boundary terms) -----------
// Two preloaded batches of 32 chunks (register-safe).
__global__ __launch_bounds__(256) void ema_carry_k(const u16* __restrict__ xpb,
                                                   const float* __restrict__ alpha,
                                                   const float* __restrict__ init,
                                                   float* __restrict__ carry) {
  const int Dd = 1024, nCh = 64;
  const int idx = blockIdx.x * 256 + threadIdx.x;  // 0..B*D-1
  const int c  = idx & (Dd - 1);
  const int bb = idx >> 10;
  const int h = c >> 7;
  const float a = 1.0f / (1.0f + __expf(-alpha[h]));
  const float r = 1.0f - a;
  // r^63 = r^(1+2+4+8+16+32)
  float t_ = r, r63 = 1.0f;
  #pragma unroll
  for (int s = 0; s < 6; ++s) { r63 *= t_; t_ *= t_; }
  const float rT = r63 * r;    // r^64
  float cin = init[c];
  float prevv = cin;                               // v_{-1} for chunk 0
  #pragma unroll
  for (int batch = 0; batch < 2; ++batch) {
    float L[32], v0[32], vm[32];
    #pragma unroll
    for (int qq = 0; qq < 32; ++qq) {
      const int q = batch * 32 + qq;
      const size_t rowb = (size_t)bb * 4096 + (size_t)q * 64;
      L[qq]  = carry[((size_t)bb * nCh + q) * Dd + c];
      v0[qq] = bf2f(xpb[rowb * Dd + c]);
      vm[qq] = bf2f(xpb[(rowb + 63) * Dd + c]);
    }
    #pragma unroll
    for (int qq = 0; qq < 32; ++qq) {
      const int q = batch * 32 + qq;
      const float Lf = L[qq] + a * r63 * (v0[qq] - prevv);
      carry[((size_t)bb * nCh + q) * Dd + c] = cin;  // incoming O for chunk q
      cin = rT * cin + Lf;
      prevv = vm[qq];
    }
  }
}

// ------- EMA apply, T=64: 1024 blocks, 1 channel/thread (2x TLP vs T=128) --
__global__ __launch_bounds__(256) void ema_apply_k(const u16* __restrict__ xp,
                                                   const float* __restrict__ alpha,
                                                   const float* __restrict__ init,
                                                   const float* __restrict__ carry,
                                                   u16* __restrict__ ob) {
  const int Nn = 4096, Dd = 1024, T = 64, nCh = 64;
  int bid = blockIdx.x;
  const int cg = bid & 3;  bid >>= 2;
  const int q  = bid & 63; bid >>= 6;
  const int bb = bid;
  const int c = cg * 256 + threadIdx.x;
  const int h = c >> 7;
  const float a = 1.0f / (1.0f + __expf(-alpha[h]));
  const float r = 1.0f - a;
  const u16* px = xp + ((size_t)bb * Nn + (size_t)q * T) * Dd + c;
  u16* po = ob + ((size_t)bb * Nn + (size_t)q * T) * Dd + c;
  float O = carry[((size_t)bb * nCh + q) * Dd + c];
  float p0 = (q == 0) ? init[c] : bf2f(px[-Dd]);
  #pragma unroll 4
  for (int t = 0; t < T; ++t) {
    const float v = bf2f(px[(size_t)t * Dd]);
    O = r * O + a * (v - p0);
    p0 = v;
    po[(size_t)t * Dd] = f2bf(O);
  }
}

extern "C" void kernel_launch(void* const* d_in, const int* in_sizes, int n_in,
                              void* d_out, int out_size, void* d_ws, size_t ws_size,
                              hipStream_t stream) {
  const float* x     = (const float*)d_in[0];
  const float* ln_g  = (const float*)d_in[1];
  const float* ln_b  = (const float*)d_in[2];
  const float* w_in  = (const float*)d_in[3];
  const float* b_in  = (const float*)d_in[4];
  const float* init  = (const float*)d_in[5];
  const float* alpha = (const float*)d_in[6];
  const float* w_out = (const float*)d_in[7];
  const float* b_out = (const float*)d_in[8];
  float* out = (float*)d_out;

  const int B = 4, N = 4096, D = 1024;
  const int M = B * N;  // 16384

  char* p = (char*)d_ws;
  u16*   xn  = (u16*)p; p += (size_t)M * D * sizeof(u16);      // 32 MB  LN out bf16
  u16*   wi  = (u16*)p; p += (size_t)D * D * sizeof(u16);      // 2 MB   w_in bf16
  u16*   wo  = (u16*)p; p += (size_t)D * D * sizeof(u16);      // 2 MB   w_out bf16
  u16*   xpb = (u16*)p; p += (size_t)M * D * sizeof(u16);      // 32 MB  xp bf16
  float* cr  = (float*)p; p += (size_t)B * 64 * D * sizeof(float); // 1 MB partials/carries
  u16*   ob  = (u16*)p;                                         // 32 MB  EMA out bf16

  // fused LN (16384 blocks) + both weight converts (2048 blocks)
  ln_cvt_k<<<dim3(M + 2048), dim3(256), 0, stream>>>(
      x, ln_g, ln_b, xn, w_in, w_out, wi, wo);
  gemm_bt_k<1><<<dim3((M / 256) * (D / 256)), dim3(512), 0, stream>>>(
      xn, wi, b_in, xpb, alpha, cr, M, D, D);
  ema_carry_k<<<dim3(B * D / 256), dim3(256), 0, stream>>>(xpb, alpha, init, cr);
  ema_apply_k<<<dim3(B * 64 * 4), dim3(256), 0, stream>>>(xpb, alpha, init, cr, ob);
  gemm_bt_k<0><<<dim3((M / 256) * (D / 256)), dim3(512), 0, stream>>>(
      ob, wo, b_out, out, nullptr, nullptr, M, D, D);
}